// Round 1
// 11793.756 us; speedup vs baseline: 1.3470x; 1.3470x over previous
//
#include <hip/hip_runtime.h>
#include <math.h>

// Problem constants (QwenMoeTransformerDecoder: B=2,S=2048,H=2048,E=8,K=4)
static constexpr int BB   = 2;
static constexpr int SS   = 2048;
static constexpr int HH   = 2048;
static constexpr int TT   = BB * SS;   // 4096 tokens
static constexpr int EE   = 8;
static constexpr int KSEL = 4;
static constexpr int IMOE = 1408;
static constexpr int ISH  = 5632;      // = 4 * IMOE (chunked)
static constexpr int NQ   = 16;
static constexpr int NKV  = 2;
static constexpr int DH   = 128;

// ---------------------------------------------------------------- RMSNorm
__global__ __launch_bounds__(256)
void rmsnorm_k(const float* __restrict__ x, const float* __restrict__ sc,
               float* __restrict__ o)
{
    const int row = blockIdx.x;
    const float4* xr = (const float4*)(x + (size_t)row * HH);
    const float4* sr = (const float4*)sc;
    float4* orow = (float4*)(o + (size_t)row * HH);
    float ss = 0.f;
    for (int i = threadIdx.x; i < HH / 4; i += 256) {
        float4 v = xr[i];
        ss += v.x * v.x + v.y * v.y + v.z * v.z + v.w * v.w;
    }
#pragma unroll
    for (int off = 32; off > 0; off >>= 1) ss += __shfl_down(ss, off, 64);
    __shared__ float red[4];
    if ((threadIdx.x & 63) == 0) red[threadIdx.x >> 6] = ss;
    __syncthreads();
    const float tot = red[0] + red[1] + red[2] + red[3];
    const float inv = rsqrtf(tot / (float)HH + 1e-5f);
    for (int i = threadIdx.x; i < HH / 4; i += 256) {
        float4 v = xr[i]; float4 s = sr[i];
        float4 w;
        w.x = v.x * inv * s.x; w.y = v.y * inv * s.y;
        w.z = v.z * inv * s.z; w.w = v.w * inv * s.w;
        orow[i] = w;
    }
}

// ---------------------------------------------------------------- zero fill (float4 granularity)
__global__ __launch_bounds__(256)
void zero_k(float* __restrict__ p, int n4)
{
    const int i = blockIdx.x * 256 + threadIdx.x;
    if (i < n4) ((float4*)p)[i] = make_float4(0.f, 0.f, 0.f, 0.f);
}

// ---------------------------------------------------------------- generic f32 GEMM
// C[m,n] = dot(A[arow?arow[m]:m,:],B[:,n]) (+bias[n]) , *rowscale[m], (+=C), (+add1), (+add2)
// Optional crow[] indirection on the C row (crow[m]<0 -> row skipped).
// Optional mlim (device ptr): blocks with m0 >= *mlim exit (sparse-expert tail).
// 64x64 tile, BK=16, 256 threads, 4x4 microtile. Grid must cover M,N exactly.
__global__ __launch_bounds__(256)
void gemm_k(const float* __restrict__ A, int lda,
            const float* __restrict__ Bm, int ldb,
            float* __restrict__ C, int ldc, int K,
            const float* __restrict__ bias,
            const float* __restrict__ rowscale,
            const float* __restrict__ add1,
            const float* __restrict__ add2,
            int accumulate,
            const int* __restrict__ arow,
            const int* __restrict__ crow,
            const int* __restrict__ mlim)
{
    const int m0 = blockIdx.y * 64;
    if (mlim && m0 >= *mlim) return;       // uniform exit, before any barrier

    __shared__ float As[16][68];   // As[k][m], pad->stride 68 (16B aligned rows)
    __shared__ float Bs[16][64];   // Bs[k][n]
    const int t  = threadIdx.x;
    const int n0 = blockIdx.x * 64;
    const int tr = t >> 4;          // 0..15 -> rows 4tr..4tr+3
    const int tc = t & 15;          // 0..15 -> cols 4tc..4tc+3
    const int ar = t >> 2;          // 0..63 A-row in tile
    const int ac = (t & 3) << 2;    // 0,4,8,12 k-offset
    const int br = t >> 4;          // 0..15 B k-row
    const int bc = (t & 15) << 2;   // 0..60 n-offset

    int arow_eff = m0 + ar;
    if (arow) { const int r = arow[arow_eff]; arow_eff = (r < 0) ? 0 : r; }
    const float* Ap = A + (size_t)arow_eff * lda + ac;
    const float* Bp = Bm + (size_t)br * ldb + n0 + bc;

    float acc[4][4] = {};
    for (int k0 = 0; k0 < K; k0 += 16) {
        const float4 av = *(const float4*)(Ap + k0);
        const float4 bv = *(const float4*)(Bp + (size_t)k0 * ldb);
        __syncthreads();
        As[ac + 0][ar] = av.x; As[ac + 1][ar] = av.y;
        As[ac + 2][ar] = av.z; As[ac + 3][ar] = av.w;
        *(float4*)&Bs[br][bc] = bv;
        __syncthreads();
#pragma unroll
        for (int kk = 0; kk < 16; ++kk) {
            const float4 a4 = *(const float4*)&As[kk][tr << 2];
            const float4 b4 = *(const float4*)&Bs[kk][tc << 2];
            const float aa[4] = {a4.x, a4.y, a4.z, a4.w};
            const float bb[4] = {b4.x, b4.y, b4.z, b4.w};
#pragma unroll
            for (int i = 0; i < 4; ++i)
#pragma unroll
                for (int j = 0; j < 4; ++j)
                    acc[i][j] += aa[i] * bb[j];
        }
    }
#pragma unroll
    for (int i = 0; i < 4; ++i) {
        const int m = m0 + (tr << 2) + i;
        int cm = m;
        if (crow) { cm = crow[m]; if (cm < 0) continue; }
        const float rs = rowscale ? rowscale[m] : 1.f;
#pragma unroll
        for (int j = 0; j < 4; ++j) {
            const int n = n0 + (tc << 2) + j;
            float v = acc[i][j];
            if (bias) v += bias[n];
            v *= rs;
            const size_t off = (size_t)cm * ldc + n;
            if (accumulate) v += C[off];
            if (add1) v += add1[off];
            if (add2) v += add2[off];
            C[off] = v;
        }
    }
}

// ---------------------------------------------------------------- RoPE (in place)
__global__ __launch_bounds__(256)
void rope_k(float* __restrict__ p, int nheads)
{
    const int idx = blockIdx.x * 256 + threadIdx.x;
    const int total = TT * nheads * (DH / 2);
    if (idx >= total) return;
    const int i  = idx & 63;
    const int hh = (idx >> 6) % nheads;
    const int tt = idx / (64 * nheads);
    const int s  = tt & (SS - 1);      // position within sequence (S pow2)
    const float freq = expf(-(float)i * (9.210340371976184f / 64.f)); // 10000^{-i/64}
    const float ang = (float)s * freq;
    float sn, cs;
    sincosf(ang, &sn, &cs);
    float* base = p + ((size_t)tt * nheads + hh) * DH;
    const float x1 = base[i], x2 = base[i + 64];
    base[i]      = x1 * cs - x2 * sn;
    base[i + 64] = x2 * cs + x1 * sn;
}

// ---------------------------------------------------------------- flash attention
// Grid (S/64, NQ, B); 256 threads. 64 queries x 32-key tiles, causal, GQA (kv = hq>>3).
// K and V share one LDS tile (K during scores, V during PV) to fit 64KB static LDS.
static constexpr int QT   = 64;
static constexpr int KT   = 32;
static constexpr int QSTR = DH + 4;   // 132 floats: 16B-aligned rows, 2-way max conflicts

__global__ __launch_bounds__(256)
void attn_k(const float* __restrict__ qb, const float* __restrict__ kb,
            const float* __restrict__ vb, float* __restrict__ ob)
{
    __shared__ float Qs[QT][QSTR];
    __shared__ float KVs[KT][QSTR];
    __shared__ float Ps[QT][KT + 1];
    __shared__ float Mrow[QT];
    __shared__ float Lrow[QT];

    const int t   = threadIdx.x;
    const int q0  = blockIdx.x * QT;
    const int hq  = blockIdx.y;
    const int bz  = blockIdx.z;
    const int kvh = hq >> 3;                    // NQ/NKV = 8
    const float scl = 0.08838834764831845f;     // 1/sqrt(128)

    for (int i4 = t; i4 < QT * (DH / 4); i4 += 256) {
        const int qi = i4 >> 5, c4 = i4 & 31;
        float4 v = *((const float4*)(qb + ((size_t)(bz * SS + q0 + qi) * NQ + hq) * DH) + c4);
        v.x *= scl; v.y *= scl; v.z *= scl; v.w *= scl;
        *(float4*)&Qs[qi][c4 << 2] = v;
    }
    if (t < QT) { Mrow[t] = -1e30f; Lrow[t] = 0.f; }

    const int tr = t >> 4;   // query group: rows 4tr..4tr+3
    const int tc = t & 15;   // keys {tc, tc+16}; O cols {4tc..4tc+3, 64+4tc..}
    float O[4][8] = {};

    const int nk = q0 + QT;
    for (int k0 = 0; k0 < nk; k0 += KT) {
        float4 kreg[4], vreg[4];
#pragma unroll
        for (int i = 0; i < 4; ++i) {
            const int idx4 = t + (i << 8);
            const int kj = idx4 >> 5, c4 = idx4 & 31;
            const size_t roff = ((size_t)(bz * SS + k0 + kj) * NKV + kvh) * DH + (c4 << 2);
            kreg[i] = *(const float4*)(kb + roff);
            vreg[i] = *(const float4*)(vb + roff);
        }
        __syncthreads();                       // prior PV done with KVs/Ps
#pragma unroll
        for (int i = 0; i < 4; ++i) {
            const int idx4 = t + (i << 8);
            *(float4*)&KVs[idx4 >> 5][(idx4 & 31) << 2] = kreg[i];
        }
        __syncthreads();                       // K tile ready

        float s0[4] = {}, s1[4] = {};
#pragma unroll 8
        for (int d = 0; d < DH; d += 4) {
            const float4 ka = *(const float4*)&KVs[tc][d];
            const float4 kb4 = *(const float4*)&KVs[tc + 16][d];
#pragma unroll
            for (int i = 0; i < 4; ++i) {
                const float4 qv = *(const float4*)&Qs[(tr << 2) + i][d];
                s0[i] += qv.x * ka.x + qv.y * ka.y + qv.z * ka.z + qv.w * ka.w;
                s1[i] += qv.x * kb4.x + qv.y * kb4.y + qv.z * kb4.z + qv.w * kb4.w;
            }
        }

#pragma unroll
        for (int i = 0; i < 4; ++i) {
            const int qg = q0 + (tr << 2) + i;
            const float a  = (k0 + tc      <= qg) ? s0[i] : -1e30f;
            const float bq_ = (k0 + tc + 16 <= qg) ? s1[i] : -1e30f;
            float mt = fmaxf(a, bq_);
#pragma unroll
            for (int o = 1; o < 16; o <<= 1) mt = fmaxf(mt, __shfl_xor(mt, o, 64));
            const float mold = Mrow[(tr << 2) + i];
            const float mnew = fmaxf(mold, mt);
            const float alpha = __expf(mold - mnew);
            const float p0 = __expf(a - mnew);
            const float p1 = __expf(bq_ - mnew);
            float ls = p0 + p1;
#pragma unroll
            for (int o = 1; o < 16; o <<= 1) ls += __shfl_xor(ls, o, 64);
            if (tc == 0) {
                Mrow[(tr << 2) + i] = mnew;
                Lrow[(tr << 2) + i] = alpha * Lrow[(tr << 2) + i] + ls;
            }
            Ps[(tr << 2) + i][tc]      = p0;
            Ps[(tr << 2) + i][tc + 16] = p1;
#pragma unroll
            for (int j = 0; j < 8; ++j) O[i][j] *= alpha;
        }
        __syncthreads();                       // everyone done reading K
#pragma unroll
        for (int i = 0; i < 4; ++i) {
            const int idx4 = t + (i << 8);
            *(float4*)&KVs[idx4 >> 5][(idx4 & 31) << 2] = vreg[i];
        }
        __syncthreads();                       // V ready, Ps visible

#pragma unroll 4
        for (int kj = 0; kj < KT; ++kj) {
            const float4 v0 = *(const float4*)&KVs[kj][tc << 2];
            const float4 v1 = *(const float4*)&KVs[kj][64 + (tc << 2)];
#pragma unroll
            for (int i = 0; i < 4; ++i) {
                const float p = Ps[(tr << 2) + i][kj];
                O[i][0] += p * v0.x; O[i][1] += p * v0.y;
                O[i][2] += p * v0.z; O[i][3] += p * v0.w;
                O[i][4] += p * v1.x; O[i][5] += p * v1.y;
                O[i][6] += p * v1.z; O[i][7] += p * v1.w;
            }
        }
    }

#pragma unroll
    for (int i = 0; i < 4; ++i) {
        const int qi = (tr << 2) + i;
        const float inv = 1.f / Lrow[qi];
        float* base = ob + ((size_t)(bz * SS + q0 + qi) * NQ + hq) * DH;
        float4 o0, o1;
        o0.x = O[i][0] * inv; o0.y = O[i][1] * inv; o0.z = O[i][2] * inv; o0.w = O[i][3] * inv;
        o1.x = O[i][4] * inv; o1.y = O[i][5] * inv; o1.z = O[i][6] * inv; o1.w = O[i][7] * inv;
        *(float4*)(base + (tc << 2)) = o0;
        *(float4*)(base + 64 + (tc << 2)) = o1;
    }
}

// ---------------------------------------------------------------- router (+ shared sigmoid gate)
__global__ __launch_bounds__(256)
void router_k(const float* __restrict__ tb, const float* __restrict__ rw,
              const float* __restrict__ sgw, float* __restrict__ dw,
              float* __restrict__ gs)
{
    const int tok = blockIdx.x;
    const float* xr = tb + (size_t)tok * HH;
    float acc[EE] = {};
    float ag = 0.f;
    for (int h = threadIdx.x; h < HH; h += 256) {
        const float xv = xr[h];
        const float4 r0 = *(const float4*)(rw + (size_t)h * EE);
        const float4 r1 = *(const float4*)(rw + (size_t)h * EE + 4);
        acc[0] += xv * r0.x; acc[1] += xv * r0.y; acc[2] += xv * r0.z; acc[3] += xv * r0.w;
        acc[4] += xv * r1.x; acc[5] += xv * r1.y; acc[6] += xv * r1.z; acc[7] += xv * r1.w;
        ag += xv * sgw[h];
    }
#pragma unroll
    for (int e = 0; e < EE; ++e)
#pragma unroll
        for (int o = 32; o > 0; o >>= 1) acc[e] += __shfl_down(acc[e], o, 64);
#pragma unroll
    for (int o = 32; o > 0; o >>= 1) ag += __shfl_down(ag, o, 64);
    __shared__ float red[4][EE + 1];
    if ((threadIdx.x & 63) == 0) {
        const int w = threadIdx.x >> 6;
#pragma unroll
        for (int e = 0; e < EE; ++e) red[w][e] = acc[e];
        red[w][EE] = ag;
    }
    __syncthreads();
    if (threadIdx.x == 0) {
        float l[EE];
#pragma unroll
        for (int e = 0; e < EE; ++e) l[e] = red[0][e] + red[1][e] + red[2][e] + red[3][e];
        const float g = red[0][EE] + red[1][EE] + red[2][EE] + red[3][EE];
        gs[tok] = 1.f / (1.f + expf(-g));
        float m = l[0];
        for (int e = 1; e < EE; ++e) m = fmaxf(m, l[e]);
        float p[EE]; float sum = 0.f;
        for (int e = 0; e < EE; ++e) { p[e] = expf(l[e] - m); sum += p[e]; }
        for (int e = 0; e < EE; ++e) p[e] /= sum;
        bool used[EE] = {};
        float wsum = 0.f;
        for (int k = 0; k < KSEL; ++k) {       // top-4, ties -> lowest index (lax.top_k)
            int bi = 0; float bv = -1.f;
            for (int e = 0; e < EE; ++e)
                if (!used[e] && p[e] > bv) { bv = p[e]; bi = e; }
            used[bi] = true; wsum += bv;
        }
        for (int e = 0; e < EE; ++e)
            dw[(size_t)tok * EE + e] = used[e] ? p[e] / wsum : 0.f;
    }
}

// ---------------------------------------------------------------- sparse-MoE routing lists
// Fixed stride-TT list region per expert (sum of counts == TT*KSEL exactly).
__global__ void route_init_k(int* __restrict__ cnt)
{
    if (threadIdx.x < EE) cnt[threadIdx.x] = 0;
}

__global__ __launch_bounds__(256)
void route_fill_k(const float* __restrict__ dw, int* __restrict__ cnt,
                  int* __restrict__ tokidx, float* __restrict__ tokw)
{
    const int t = blockIdx.x * 256 + threadIdx.x;
    if (t >= TT) return;
#pragma unroll
    for (int e = 0; e < EE; ++e) {
        const float w = dw[(size_t)t * EE + e];
        if (w > 0.f) {
            const int pos = atomicAdd(cnt + e, 1);
            tokidx[e * TT + pos] = t;
            tokw[e * TT + pos]   = w;
        }
    }
}

// pad each expert's list to a multiple of 64 (GEMM M-tile) with -1 sentinels
__global__ void route_pad_k(const int* __restrict__ cnt, int* __restrict__ mpad,
                            int* __restrict__ tokidx)
{
    const int e = blockIdx.x;
    const int c = cnt[e];
    const int mp = (c + 63) & ~63;
    if (threadIdx.x == 0) mpad[e] = mp;
    for (int i = c + threadIdx.x; i < mp; i += 64) tokidx[e * TT + i] = -1;
}

// ---------------------------------------------------------------- silu(g)*u (*dw[token,e]), optional row limit
__global__ __launch_bounds__(256)
void silu_mul_k(float* __restrict__ g, const float* __restrict__ u,
                const float* __restrict__ dw, int ecol, int icols, int n,
                const int* __restrict__ mlim)
{
    const int idx = blockIdx.x * 256 + threadIdx.x;
    if (idx >= n) return;
    if (mlim && idx >= (*mlim) * icols) return;
    const float gv = g[idx];
    const float uv = u[idx];
    float v = gv / (1.f + __expf(-gv)) * uv;
    if (dw) v *= dw[(size_t)(idx / icols) * EE + ecol];
    g[idx] = v;
}

// ---------------------------------------------------------------- launcher
extern "C" void kernel_launch(void* const* d_in, const int* in_sizes, int n_in,
                              void* d_out, int out_size, void* d_ws, size_t ws_size,
                              hipStream_t stream)
{
    (void)in_sizes; (void)n_in; (void)out_size;
    const float* x   = (const float*)d_in[0];
    const float* ln1 = (const float*)d_in[1];
    const float* wq  = (const float*)d_in[2];
    const float* bq  = (const float*)d_in[3];
    const float* wk  = (const float*)d_in[4];
    const float* bk  = (const float*)d_in[5];
    const float* wv  = (const float*)d_in[6];
    const float* bv  = (const float*)d_in[7];
    const float* wo  = (const float*)d_in[8];
    const float* ln2 = (const float*)d_in[9];
    const float* rww = (const float*)d_in[10];
    const float* wg  = (const float*)d_in[11];
    const float* wu  = (const float*)d_in[12];
    const float* wd  = (const float*)d_in[13];
    const float* swg = (const float*)d_in[14];
    const float* swu = (const float*)d_in[15];
    const float* swd = (const float*)d_in[16];
    const float* sgw = (const float*)d_in[17];
    float* out = (float*)d_out;

    // workspace layout (f32); attnb aliases hbuf, tb aliases qb
    float* ws   = (float*)d_ws;
    float* hbuf = ws;
    float* qb   = hbuf + (size_t)TT * HH;
    float* kb   = qb   + (size_t)TT * NQ * DH;
    float* vb   = kb   + (size_t)TT * NKV * DH;
    float* x1   = vb   + (size_t)TT * NKV * DH;
    float* moe  = x1   + (size_t)TT * HH;
    float* gbuf = moe  + (size_t)TT * HH;
    float* ubuf = gbuf + (size_t)TT * IMOE;
    float* dw   = ubuf + (size_t)TT * IMOE;
    float* gs   = dw   + (size_t)TT * EE;
    int*   tokidx = (int*)(gs + TT);                 // [EE][TT]
    float* tokw   = (float*)(tokidx + (size_t)EE * TT); // [EE][TT]
    int*   cnt    = (int*)(tokw + (size_t)EE * TT);  // [EE]
    int*   mpad   = cnt + EE;                        // [EE]
    const size_t need_bytes = (size_t)((char*)(mpad + EE) - (char*)ws);
    if (ws_size < need_bytes) return;                // workspace too small

    float* attnb = hbuf;   // hbuf dead after q/k/v projections
    float* tb    = qb;     // qb dead after attention

    // 1) pre-norm
    rmsnorm_k<<<TT, 256, 0, stream>>>(x, ln1, hbuf);
    // 2) q/k/v projections (+bias)
    gemm_k<<<dim3((NQ * DH) / 64, TT / 64), 256, 0, stream>>>(hbuf, HH, wq, NQ * DH, qb, NQ * DH, HH, bq, nullptr, nullptr, nullptr, 0, nullptr, nullptr, nullptr);
    gemm_k<<<dim3((NKV * DH) / 64, TT / 64), 256, 0, stream>>>(hbuf, HH, wk, NKV * DH, kb, NKV * DH, HH, bk, nullptr, nullptr, nullptr, 0, nullptr, nullptr, nullptr);
    gemm_k<<<dim3((NKV * DH) / 64, TT / 64), 256, 0, stream>>>(hbuf, HH, wv, NKV * DH, vb, NKV * DH, HH, bv, nullptr, nullptr, nullptr, 0, nullptr, nullptr, nullptr);
    // 3) RoPE
    rope_k<<<(TT * NQ * 64 + 255) / 256, 256, 0, stream>>>(qb, NQ);
    rope_k<<<(TT * NKV * 64 + 255) / 256, 256, 0, stream>>>(kb, NKV);
    // 4) causal GQA attention
    attn_k<<<dim3(SS / QT, NQ, BB), 256, 0, stream>>>(qb, kb, vb, attnb);
    // 5) output projection + residual
    gemm_k<<<dim3(HH / 64, TT / 64), 256, 0, stream>>>(attnb, NQ * DH, wo, HH, x1, HH, NQ * DH, nullptr, nullptr, x, nullptr, 0, nullptr, nullptr, nullptr);
    // 6) post-attn norm + router (+ shared sigmoid gate)
    rmsnorm_k<<<TT, 256, 0, stream>>>(x1, ln2, tb);
    router_k<<<TT, 256, 0, stream>>>(tb, rww, sgw, dw, gs);
    // 6b) sparse routing lists + zero the MoE accumulator
    zero_k<<<(TT * HH / 4 + 255) / 256, 256, 0, stream>>>(moe, TT * HH / 4);
    route_init_k<<<1, 64, 0, stream>>>(cnt);
    route_fill_k<<<(TT + 255) / 256, 256, 0, stream>>>(dw, cnt, tokidx, tokw);
    route_pad_k<<<EE, 64, 0, stream>>>(cnt, mpad, tokidx);
    // 7) experts — SPARSE: only tokens routed to expert e (avg ~T*K/E rows).
    //    gate/up gather A rows via tokidx; down scatter-accumulates into moe
    //    with per-row routing weight (matches reference: weight applied AFTER down-proj).
    const int nmoe = TT * IMOE;
    for (int e = 0; e < EE; ++e) {
        const float* wge = wg + (size_t)e * HH * IMOE;
        const float* wue = wu + (size_t)e * HH * IMOE;
        const float* wde = wd + (size_t)e * IMOE * HH;
        const int*   idx = tokidx + e * TT;
        const float* twe = tokw + e * TT;
        const int*   ml  = mpad + e;
        gemm_k<<<dim3(IMOE / 64, TT / 64), 256, 0, stream>>>(tb, HH, wge, IMOE, gbuf, IMOE, HH, nullptr, nullptr, nullptr, nullptr, 0, idx, nullptr, ml);
        gemm_k<<<dim3(IMOE / 64, TT / 64), 256, 0, stream>>>(tb, HH, wue, IMOE, ubuf, IMOE, HH, nullptr, nullptr, nullptr, nullptr, 0, idx, nullptr, ml);
        silu_mul_k<<<(nmoe + 255) / 256, 256, 0, stream>>>(gbuf, ubuf, nullptr, 0, IMOE, nmoe, ml);
        gemm_k<<<dim3(HH / 64, TT / 64), 256, 0, stream>>>(gbuf, IMOE, wde, HH, moe, HH, IMOE, nullptr, twe, nullptr, nullptr, 1, nullptr, idx, ml);
    }
    // 8) shared expert, chunked over I_SH in 4 x 1408; last chunk fuses final residual sum
    for (int c = 0; c < 4; ++c) {
        const float* swgc = swg + (size_t)c * IMOE;          // column block, ldb = ISH
        const float* swuc = swu + (size_t)c * IMOE;
        const float* swdc = swd + (size_t)c * IMOE * HH;     // row block
        gemm_k<<<dim3(IMOE / 64, TT / 64), 256, 0, stream>>>(tb, HH, swgc, ISH, gbuf, IMOE, HH, nullptr, nullptr, nullptr, nullptr, 0, nullptr, nullptr, nullptr);
        gemm_k<<<dim3(IMOE / 64, TT / 64), 256, 0, stream>>>(tb, HH, swuc, ISH, ubuf, IMOE, HH, nullptr, nullptr, nullptr, nullptr, 0, nullptr, nullptr, nullptr);
        silu_mul_k<<<(nmoe + 255) / 256, 256, 0, stream>>>(gbuf, ubuf, nullptr, 0, IMOE, nmoe, nullptr);
        if (c < 3)
            gemm_k<<<dim3(HH / 64, TT / 64), 256, 0, stream>>>(gbuf, IMOE, swdc, HH, moe, HH, IMOE, nullptr, gs, nullptr, nullptr, 1, nullptr, nullptr, nullptr);
        else  // out = x1 + moe + gs .* (hs_c @ swdown_c)
            gemm_k<<<dim3(HH / 64, TT / 64), 256, 0, stream>>>(gbuf, IMOE, swdc, HH, out, HH, IMOE, nullptr, gs, moe, x1, 0, nullptr, nullptr, nullptr);
    }
}